// Round 4
// baseline (1333.644 us; speedup 1.0000x reference)
//
#include <hip/hip_runtime.h>
#include <math.h>

typedef __attribute__((ext_vector_type(8))) _Float16 f16x8;
typedef __attribute__((ext_vector_type(4))) _Float16 f16x4;
typedef __attribute__((ext_vector_type(4))) float f32x4;

// ---------------------------------------------------------------------------
// Precision: split-fp16 planes a = ah + al/2048 (al stored x2048).
// C = ah@wh + (ah@wl_s + al_s@wh)/2048 -> ~2^-22 rel (fp32-grade), needed
// because out = pos/(|pos|+1e-8) amplifies pos error ~10^2-10^3 x.
// Aggregation in fp32 (msc fp32), feature-chunked for per-XCD L2 residency.
// ---------------------------------------------------------------------------

// ------------------------- graph setup -------------------------------------
__global__ void count_kernel(const int* __restrict__ dst, int E, int* __restrict__ cnt) {
    int i = blockIdx.x * blockDim.x + threadIdx.x;
    if (i < E) atomicAdd(&cnt[dst[i]], 1);
}

__global__ void scan1_kernel(const int* __restrict__ cnt, int M,
                             int* __restrict__ rowptr, int* __restrict__ bsum,
                             float* __restrict__ dinv) {
    __shared__ int s[256];
    int t = threadIdx.x;
    int i = blockIdx.x * 256 + t;
    int v = (i < M) ? cnt[i] : 0;
    s[t] = v; __syncthreads();
    for (int o = 1; o < 256; o <<= 1) {
        int x = (t >= o) ? s[t - o] : 0;
        __syncthreads();
        s[t] += x;
        __syncthreads();
    }
    if (i < M) {
        rowptr[i] = s[t] - v;
        dinv[i] = rsqrtf((float)v + 1.0f);  // deg = in-deg + self-loop
    }
    if (t == 255) bsum[blockIdx.x] = s[255];
}

__global__ void scan2_kernel(const int* __restrict__ bsum, int nb, int* __restrict__ boff) {
    __shared__ int s[256];
    int t = threadIdx.x;
    int v = (t < nb) ? bsum[t] : 0;
    s[t] = v; __syncthreads();
    for (int o = 1; o < 256; o <<= 1) {
        int x = (t >= o) ? s[t - o] : 0;
        __syncthreads();
        s[t] += x;
        __syncthreads();
    }
    if (t < nb) boff[t] = s[t] - v;
}

__global__ void scan3_kernel(int* __restrict__ rowptr, int M, int E, const int* __restrict__ boff) {
    int i = blockIdx.x * 256 + threadIdx.x;
    if (i < M) rowptr[i] += boff[blockIdx.x];
    if (i == M) rowptr[M] = E;
}

__global__ void fill_kernel(const int* __restrict__ src, const int* __restrict__ dst, int E,
                            const int* __restrict__ rowptr, int* __restrict__ cursor,
                            int* __restrict__ csr) {
    int i = blockIdx.x * blockDim.x + threadIdx.x;
    if (i < E) {
        int d = dst[i];
        int slot = atomicAdd(&cursor[d], 1);
        csr[rowptr[d] + slot] = src[i];
    }
}

// ------------------------- converters --------------------------------------
__global__ void convert_x_kernel(const float* __restrict__ x, _Float16* __restrict__ xh,
                                 _Float16* __restrict__ xl, int n4) {
    int i = blockIdx.x * 256 + threadIdx.x;
    if (i < n4) {
        float4 v = reinterpret_cast<const float4*>(x)[i];
        f16x4 h = {(_Float16)v.x, (_Float16)v.y, (_Float16)v.z, (_Float16)v.w};
        reinterpret_cast<f16x4*>(xh)[i] = h;
        f16x4 l = {(_Float16)((v.x - (float)h[0]) * 2048.f),
                   (_Float16)((v.y - (float)h[1]) * 2048.f),
                   (_Float16)((v.z - (float)h[2]) * 2048.f),
                   (_Float16)((v.w - (float)h[3]) * 2048.f)};
        reinterpret_cast<f16x4*>(xl)[i] = l;
    }
}

struct WSeg { const float* src; _Float16* dh; _Float16* dl; int K; int N; };
struct WSegs { WSeg s[8]; };

// dh/dl transposed planes: WT[n][k] = W[k][n]
__global__ void convert_wt_kernel(WSegs segs) {
    WSeg sg = segs.s[blockIdx.y];
    int i = blockIdx.x * 256 + threadIdx.x;
    if (i < sg.K * sg.N) {
        int n = i / sg.K, k = i - n * sg.K;
        float w = sg.src[(size_t)k * sg.N + n];
        _Float16 hi = (_Float16)w;
        sg.dh[i] = hi;
        sg.dl[i] = (_Float16)((w - (float)hi) * 2048.f);
    }
}

// ---------------------------------------------------------------------------
// LDS-free split-fp16 MFMA GEMM. 256 threads = 4 waves, no LDS, no barriers.
// Fragments loaded straight from global (A slice L1-resident, B L2-resident).
//   NN=192: ROWS=32; all waves share rows, wave w -> cols [w*48, +48)
//   NN=96 : ROWS=64; wave w -> rows [(w>>1)*32..), cols [(w&1)*48..)
// Per wave: 2 m-tiles x 3 n-tiles x (KK/32) ksteps x 3 MFMA (16x16x32 f16).
// OM bit0: fp32 out Cf; bit1: fp16 plane out (Ch, Cl x2048). rowscale last.
// ---------------------------------------------------------------------------
template <int KK, int NN, int ACT, int OM>
__global__ __launch_bounds__(256) void mfma_gemm(
    const _Float16* __restrict__ Ah, const _Float16* __restrict__ Al,
    const _Float16* __restrict__ WhT, const _Float16* __restrict__ WlT,
    const float* __restrict__ bias, const float* __restrict__ rowscale,
    float* __restrict__ Cf, _Float16* __restrict__ Ch, _Float16* __restrict__ Cl,
    int M) {
    constexpr int ROWS = (NN == 192) ? 32 : 64;
    const int tid = threadIdx.x;
    const int wave = tid >> 6, lane = tid & 63;
    const int quad = lane >> 4, l16 = lane & 15;
    const int m0 = (NN == 192) ? 0 : (wave >> 1) * 32;
    const int n0 = (NN == 192) ? wave * 48 : (wave & 1) * 48;
    const int row0 = blockIdx.x * ROWS;

    const int rA0 = row0 + m0 + l16;
    const int rA1 = rA0 + 16;
    const bool ok0 = rA0 < M, ok1 = rA1 < M;
    const size_t a0off = (size_t)rA0 * KK;
    const size_t a1off = (size_t)rA1 * KK;
    const size_t boff = (size_t)(n0 + l16) * KK;

    f32x4 acc[2][3], acc2[2][3];
#pragma unroll
    for (int mt = 0; mt < 2; ++mt)
#pragma unroll
        for (int nt = 0; nt < 3; ++nt) {
            acc[mt][nt] = (f32x4){0.f, 0.f, 0.f, 0.f};
            acc2[mt][nt] = (f32x4){0.f, 0.f, 0.f, 0.f};
        }

#pragma unroll
    for (int ks = 0; ks < KK; ks += 32) {
        const int k0 = ks + quad * 8;
        f16x8 ah0 = {}, al0 = {}, ah1 = {}, al1 = {};
        if (ok0) {
            ah0 = *reinterpret_cast<const f16x8*>(Ah + a0off + k0);
            al0 = *reinterpret_cast<const f16x8*>(Al + a0off + k0);
        }
        if (ok1) {
            ah1 = *reinterpret_cast<const f16x8*>(Ah + a1off + k0);
            al1 = *reinterpret_cast<const f16x8*>(Al + a1off + k0);
        }
        f16x8 bh[3], bl[3];
#pragma unroll
        for (int nt = 0; nt < 3; ++nt) {
            bh[nt] = *reinterpret_cast<const f16x8*>(WhT + boff + (size_t)nt * 16 * KK + k0);
            bl[nt] = *reinterpret_cast<const f16x8*>(WlT + boff + (size_t)nt * 16 * KK + k0);
        }
#pragma unroll
        for (int nt = 0; nt < 3; ++nt) {
            acc[0][nt] = __builtin_amdgcn_mfma_f32_16x16x32_f16(ah0, bh[nt], acc[0][nt], 0, 0, 0);
            acc2[0][nt] = __builtin_amdgcn_mfma_f32_16x16x32_f16(ah0, bl[nt], acc2[0][nt], 0, 0, 0);
            acc2[0][nt] = __builtin_amdgcn_mfma_f32_16x16x32_f16(al0, bh[nt], acc2[0][nt], 0, 0, 0);
            acc[1][nt] = __builtin_amdgcn_mfma_f32_16x16x32_f16(ah1, bh[nt], acc[1][nt], 0, 0, 0);
            acc2[1][nt] = __builtin_amdgcn_mfma_f32_16x16x32_f16(ah1, bl[nt], acc2[1][nt], 0, 0, 0);
            acc2[1][nt] = __builtin_amdgcn_mfma_f32_16x16x32_f16(al1, bh[nt], acc2[1][nt], 0, 0, 0);
        }
    }

    // epilogue: C/D layout col=lane&15, row=quad*4+reg
    float bv[3];
#pragma unroll
    for (int nt = 0; nt < 3; ++nt) bv[nt] = bias ? bias[n0 + nt * 16 + l16] : 0.f;
#pragma unroll
    for (int mt = 0; mt < 2; ++mt)
#pragma unroll
        for (int i = 0; i < 4; ++i) {
            int row = row0 + m0 + mt * 16 + quad * 4 + i;
            if (row < M) {
                float rs = rowscale ? rowscale[row] : 1.f;
#pragma unroll
                for (int nt = 0; nt < 3; ++nt) {
                    int col = n0 + nt * 16 + l16;
                    float v = acc[mt][nt][i] + acc2[mt][nt][i] * (1.f / 2048.f) + bv[nt];
                    if (ACT == 1) v = fmaxf(v, 0.f);
                    v *= rs;
                    if (OM & 1) Cf[(size_t)row * NN + col] = v;
                    if (OM & 2) {
                        _Float16 hi = (_Float16)v;
                        Ch[(size_t)row * NN + col] = hi;
                        Cl[(size_t)row * NN + col] = (_Float16)((v - (float)hi) * 2048.f);
                    }
                }
            }
        }
}

// ---------------------------------------------------------------------------
// Feature-chunked fp32 aggregation. 12 chunks x 16 floats: per-chunk msc
// slice = M*64 B = 3.2 MB < 4 MiB per-XCD L2. Chunk-major block order so the
// whole GPU works one chunk at a time -> slice L2-resident on every XCD.
// Block = 256 thr = 64 nodes x 4 float4-cols of the chunk.
// h = h + relu(dinv[n]*(msc[n]+sum msc[src]) + B), h kept as fp16 planes.
// ---------------------------------------------------------------------------
__global__ __launch_bounds__(256) void aggregate_kernel(
    const float* __restrict__ msc, const int* __restrict__ csr,
    const int* __restrict__ rowptr, const float* __restrict__ dinv,
    const float* __restrict__ bias, _Float16* __restrict__ h_hi,
    _Float16* __restrict__ h_lo, int M, int NG) {
    const int chunk = blockIdx.x / NG;
    const int g = blockIdx.x - chunk * NG;
    const int t = threadIdx.x;
    const int node = g * 64 + (t >> 2);
    if (node >= M) return;
    const int col = chunk * 4 + (t & 3);  // float4 col in [0,48)

    const float4* m4 = reinterpret_cast<const float4*>(msc);
    float4 a = m4[(size_t)node * 48 + col];  // self-loop (already * dinv[node])
    float4 a2 = make_float4(0.f, 0.f, 0.f, 0.f);
    const int beg = rowptr[node], end = rowptr[node + 1];
    int e = beg;
    for (; e + 1 < end; e += 2) {
        int s0 = csr[e], s1 = csr[e + 1];
        float4 v0 = m4[(size_t)s0 * 48 + col];
        float4 v1 = m4[(size_t)s1 * 48 + col];
        a.x += v0.x; a.y += v0.y; a.z += v0.z; a.w += v0.w;
        a2.x += v1.x; a2.y += v1.y; a2.z += v1.z; a2.w += v1.w;
    }
    if (e < end) {
        float4 v = m4[(size_t)csr[e] * 48 + col];
        a.x += v.x; a.y += v.y; a.z += v.z; a.w += v.w;
    }
    a.x += a2.x; a.y += a2.y; a.z += a2.z; a.w += a2.w;

    float dn = dinv[node];
    float4 b = reinterpret_cast<const float4*>(bias)[col];
    f16x4* hp = reinterpret_cast<f16x4*>(h_hi) + (size_t)node * 48 + col;
    f16x4* lp = reinterpret_cast<f16x4*>(h_lo) + (size_t)node * 48 + col;
    f16x4 hh = *hp, hl = *lp;
    float4 hv;
    hv.x = (float)hh[0] + (float)hl[0] * (1.f / 2048.f) + fmaxf(a.x * dn + b.x, 0.f);
    hv.y = (float)hh[1] + (float)hl[1] * (1.f / 2048.f) + fmaxf(a.y * dn + b.y, 0.f);
    hv.z = (float)hh[2] + (float)hl[2] * (1.f / 2048.f) + fmaxf(a.z * dn + b.z, 0.f);
    hv.w = (float)hh[3] + (float)hl[3] * (1.f / 2048.f) + fmaxf(a.w * dn + b.w, 0.f);
    f16x4 nh = {(_Float16)hv.x, (_Float16)hv.y, (_Float16)hv.z, (_Float16)hv.w};
    f16x4 nl = {(_Float16)((hv.x - (float)nh[0]) * 2048.f),
                (_Float16)((hv.y - (float)nh[1]) * 2048.f),
                (_Float16)((hv.z - (float)nh[2]) * 2048.f),
                (_Float16)((hv.w - (float)nh[3]) * 2048.f)};
    *hp = nh;
    *lp = nl;
}

// ---------------------------------------------------------------------------
// Tail: pos = p2@Wp3+bp3; rad = sigmoid(r@Wr2+br2); out = pos/(|pos|+1e-8)*rad
// ---------------------------------------------------------------------------
__global__ void finalize_kernel(const float* __restrict__ p2, const float* __restrict__ rbuf,
                                const float* __restrict__ Wp3, const float* __restrict__ bp3,
                                const float* __restrict__ Wr2, const float* __restrict__ br2,
                                float* __restrict__ out, int M) {
    int n = blockIdx.x * 256 + threadIdx.x;
    if (n >= M) return;
    const float4* p = reinterpret_cast<const float4*>(p2 + (size_t)n * 96);
    const float4* r = reinterpret_cast<const float4*>(rbuf + (size_t)n * 96);
    float a0 = 0.f, a1 = 0.f, rr = 0.f;
#pragma unroll
    for (int q = 0; q < 24; q++) {
        float4 pv = p[q];
        float4 rv = r[q];
        float4 w01 = reinterpret_cast<const float4*>(Wp3)[2 * q];
        float4 w23 = reinterpret_cast<const float4*>(Wp3)[2 * q + 1];
        a0 += pv.x * w01.x + pv.y * w01.z + pv.z * w23.x + pv.w * w23.z;
        a1 += pv.x * w01.y + pv.y * w01.w + pv.z * w23.y + pv.w * w23.w;
        float4 wr = reinterpret_cast<const float4*>(Wr2)[q];
        rr += rv.x * wr.x + rv.y * wr.y + rv.z * wr.z + rv.w * wr.w;
    }
    a0 += bp3[0];
    a1 += bp3[1];
    rr += br2[0];
    float radius = 1.f / (1.f + expf(-rr));
    float nrm = sqrtf(a0 * a0 + a1 * a1) + 1e-8f;
    float s = radius / nrm;
    out[(size_t)n * 2 + 0] = a0 * s;
    out[(size_t)n * 2 + 1] = a1 * s;
}

extern "C" void kernel_launch(void* const* d_in, const int* in_sizes, int n_in,
                              void* d_out, int out_size, void* d_ws, size_t ws_size,
                              hipStream_t stream) {
    const float* x     = (const float*)d_in[0];
    const int*   ei    = (const int*)d_in[1];
    const float* Wp    = (const float*)d_in[2];
    const float* bp    = (const float*)d_in[3];
    const float* convW = (const float*)d_in[4];
    const float* convB = (const float*)d_in[5];
    const float* Wp1   = (const float*)d_in[6];
    const float* bp1   = (const float*)d_in[7];
    const float* Wp2   = (const float*)d_in[8];
    const float* bp2   = (const float*)d_in[9];
    const float* Wp3   = (const float*)d_in[10];
    const float* bp3   = (const float*)d_in[11];
    const float* Wr1   = (const float*)d_in[12];
    const float* br1   = (const float*)d_in[13];
    const float* Wr2   = (const float*)d_in[14];
    const float* br2   = (const float*)d_in[15];
    float* out = (float*)d_out;

    const int M = in_sizes[0] / 128;  // 50000
    const int E = in_sizes[1] / 2;    // 800000
    const int* srcI = ei;
    const int* dstI = ei + E;

    char* w = (char*)d_ws;
    size_t off = 0;
    auto alloc = [&](size_t b) { size_t o = off; off += (b + 255) & ~(size_t)255; return o; };
    float*    msc  = (float*)(w + alloc((size_t)M * 192 * 4));
    _Float16* h_hi = (_Float16*)(w + alloc((size_t)M * 192 * 2));
    _Float16* h_lo = (_Float16*)(w + alloc((size_t)M * 192 * 2));
    char*     xreg = w + alloc((size_t)M * 128 * 2 * 2);  // xh+xl; later p2 fp32
    float*    rb   = (float*)(w + alloc((size_t)M * 96 * 4));
    _Float16* WphT  = (_Float16*)(w + alloc((size_t)128 * 192 * 2));
    _Float16* WplT  = (_Float16*)(w + alloc((size_t)128 * 192 * 2));
    _Float16* cWhT  = (_Float16*)(w + alloc((size_t)4 * 192 * 192 * 2));
    _Float16* cWlT  = (_Float16*)(w + alloc((size_t)4 * 192 * 192 * 2));
    _Float16* Wp1hT = (_Float16*)(w + alloc((size_t)192 * 192 * 2));
    _Float16* Wp1lT = (_Float16*)(w + alloc((size_t)192 * 192 * 2));
    _Float16* Wp2hT = (_Float16*)(w + alloc((size_t)96 * 192 * 2));
    _Float16* Wp2lT = (_Float16*)(w + alloc((size_t)96 * 192 * 2));
    _Float16* Wr1hT = (_Float16*)(w + alloc((size_t)96 * 192 * 2));
    _Float16* Wr1lT = (_Float16*)(w + alloc((size_t)96 * 192 * 2));
    int*      cnt    = (int*)(w + alloc((size_t)M * 4));
    float*    dinv   = (float*)(w + alloc((size_t)M * 4));
    int*      rowptr = (int*)(w + alloc((size_t)(M + 1) * 4));
    int*      cursor = (int*)(w + alloc((size_t)M * 4));
    int*      csr    = (int*)(w + alloc((size_t)E * 4));
    int*      bsum   = (int*)(w + alloc(256 * 4));
    int*      boff   = (int*)(w + alloc(256 * 4));

    _Float16* xh  = (_Float16*)xreg;
    _Float16* xl  = xh + (size_t)M * 128;
    float*    p2  = (float*)xreg;           // alias: x planes dead after proj
    _Float16* p1h = (_Float16*)msc;         // alias: msc dead after last aggregate
    _Float16* p1l = p1h + (size_t)M * 192;

    hipMemsetAsync(cnt, 0, (size_t)M * 4, stream);
    hipMemsetAsync(cursor, 0, (size_t)M * 4, stream);

    // graph setup
    count_kernel<<<(E + 255) / 256, 256, 0, stream>>>(dstI, E, cnt);
    int nb = (M + 255) / 256;
    scan1_kernel<<<nb, 256, 0, stream>>>(cnt, M, rowptr, bsum, dinv);
    scan2_kernel<<<1, 256, 0, stream>>>(bsum, nb, boff);
    scan3_kernel<<<(M + 256) / 256, 256, 0, stream>>>(rowptr, M, E, boff);
    fill_kernel<<<(E + 255) / 256, 256, 0, stream>>>(srcI, dstI, E, rowptr, cursor, csr);

    // conversions
    convert_x_kernel<<<((M * 128 / 4) + 255) / 256, 256, 0, stream>>>(x, xh, xl, M * 128 / 4);
    WSegs segs;
    segs.s[0] = {Wp, WphT, WplT, 128, 192};
    segs.s[1] = {convW + 0 * 192 * 192, cWhT + 0 * 192 * 192, cWlT + 0 * 192 * 192, 192, 192};
    segs.s[2] = {convW + 1 * 192 * 192, cWhT + 1 * 192 * 192, cWlT + 1 * 192 * 192, 192, 192};
    segs.s[3] = {convW + 2 * 192 * 192, cWhT + 2 * 192 * 192, cWlT + 2 * 192 * 192, 192, 192};
    segs.s[4] = {convW + 3 * 192 * 192, cWhT + 3 * 192 * 192, cWlT + 3 * 192 * 192, 192, 192};
    segs.s[5] = {Wp1, Wp1hT, Wp1lT, 192, 192};
    segs.s[6] = {Wp2, Wp2hT, Wp2lT, 192, 96};
    segs.s[7] = {Wr1, Wr1hT, Wr1lT, 192, 96};
    convert_wt_kernel<<<dim3(144, 8), 256, 0, stream>>>(segs);

    const int gb192 = (M + 31) / 32;   // 1563 blocks (32 rows each)
    const int gb96  = (M + 63) / 64;   // 782 blocks (64 rows each)
    const int NG    = (M + 63) / 64;   // aggregate node-groups
    const int aggGrid = 12 * NG;       // 12 feature chunks, chunk-major

    // h = x @ Wp + bp -> planes
    mfma_gemm<128, 192, 0, 2><<<gb192, 256, 0, stream>>>(
        xh, xl, WphT, WplT, bp, nullptr, nullptr, h_hi, h_lo, M);
    // 4 GCN layers
    for (int i = 0; i < 4; i++) {
        mfma_gemm<192, 192, 0, 1><<<gb192, 256, 0, stream>>>(
            h_hi, h_lo, cWhT + (size_t)i * 192 * 192, cWlT + (size_t)i * 192 * 192,
            nullptr, dinv, msc, nullptr, nullptr, M);
        aggregate_kernel<<<aggGrid, 256, 0, stream>>>(
            msc, csr, rowptr, dinv, convB + (size_t)i * 192, h_hi, h_lo, M, NG);
    }
    // heads
    mfma_gemm<192, 192, 1, 2><<<gb192, 256, 0, stream>>>(
        h_hi, h_lo, Wp1hT, Wp1lT, bp1, nullptr, nullptr, p1h, p1l, M);
    mfma_gemm<192, 96, 1, 1><<<gb96, 256, 0, stream>>>(
        p1h, p1l, Wp2hT, Wp2lT, bp2, nullptr, p2, nullptr, nullptr, M);
    mfma_gemm<192, 96, 1, 1><<<gb96, 256, 0, stream>>>(
        h_hi, h_lo, Wr1hT, Wr1lT, br1, nullptr, rb, nullptr, nullptr, M);
    finalize_kernel<<<(M + 255) / 256, 256, 0, stream>>>(p2, rb, Wp3, bp3, Wr2, br2, out, M);
}

// Round 5
// 766.353 us; speedup vs baseline: 1.7402x; 1.7402x over previous
//
#include <hip/hip_runtime.h>
#include <math.h>

typedef __attribute__((ext_vector_type(8))) _Float16 f16x8;
typedef __attribute__((ext_vector_type(4))) _Float16 f16x4;
typedef __attribute__((ext_vector_type(4))) float f32x4;

// ---------------------------------------------------------------------------
// Precision: split-fp16 planes a = ah + al/2048 (al stored x2048).
// C = ah@wh + (ah@wl_s + al_s@wh)/2048 -> ~2^-22 rel (fp32-grade); needed
// because out = pos/(|pos|+1e-8) amplifies pos error ~600x.
// GEMM: m97-style global_load_lds(16B) + double-buffered BK=32 slabs,
// XOR-swizzled LDS rows (no padding allowed with global_load_lds).
// Aggregation: round-3 whole-row design (chunking regressed: 578 vs 311 MB).
// ---------------------------------------------------------------------------

// ------------------------- graph setup -------------------------------------
__global__ void count_kernel(const int* __restrict__ dst, int E, int* __restrict__ cnt) {
    int i = blockIdx.x * blockDim.x + threadIdx.x;
    if (i < E) atomicAdd(&cnt[dst[i]], 1);
}

__global__ void scan1_kernel(const int* __restrict__ cnt, int M,
                             int* __restrict__ rowptr, int* __restrict__ bsum,
                             float* __restrict__ dinv) {
    __shared__ int s[256];
    int t = threadIdx.x;
    int i = blockIdx.x * 256 + t;
    int v = (i < M) ? cnt[i] : 0;
    s[t] = v; __syncthreads();
    for (int o = 1; o < 256; o <<= 1) {
        int x = (t >= o) ? s[t - o] : 0;
        __syncthreads();
        s[t] += x;
        __syncthreads();
    }
    if (i < M) {
        rowptr[i] = s[t] - v;
        dinv[i] = rsqrtf((float)v + 1.0f);  // deg = in-deg + self-loop
    }
    if (t == 255) bsum[blockIdx.x] = s[255];
}

__global__ void scan2_kernel(const int* __restrict__ bsum, int nb, int* __restrict__ boff) {
    __shared__ int s[256];
    int t = threadIdx.x;
    int v = (t < nb) ? bsum[t] : 0;
    s[t] = v; __syncthreads();
    for (int o = 1; o < 256; o <<= 1) {
        int x = (t >= o) ? s[t - o] : 0;
        __syncthreads();
        s[t] += x;
        __syncthreads();
    }
    if (t < nb) boff[t] = s[t] - v;
}

__global__ void scan3_kernel(int* __restrict__ rowptr, int M, int E, const int* __restrict__ boff) {
    int i = blockIdx.x * 256 + threadIdx.x;
    if (i < M) rowptr[i] += boff[blockIdx.x];
    if (i == M) rowptr[M] = E;
}

__global__ void fill_kernel(const int* __restrict__ src, const int* __restrict__ dst, int E,
                            const int* __restrict__ rowptr, int* __restrict__ cursor,
                            int* __restrict__ csr) {
    int i = blockIdx.x * blockDim.x + threadIdx.x;
    if (i < E) {
        int d = dst[i];
        int slot = atomicAdd(&cursor[d], 1);
        csr[rowptr[d] + slot] = src[i];
    }
}

// ------------------------- converters --------------------------------------
__global__ void convert_x_kernel(const float* __restrict__ x, _Float16* __restrict__ xh,
                                 _Float16* __restrict__ xl, int n4) {
    int i = blockIdx.x * 256 + threadIdx.x;
    if (i < n4) {
        float4 v = reinterpret_cast<const float4*>(x)[i];
        f16x4 h = {(_Float16)v.x, (_Float16)v.y, (_Float16)v.z, (_Float16)v.w};
        reinterpret_cast<f16x4*>(xh)[i] = h;
        f16x4 l = {(_Float16)((v.x - (float)h[0]) * 2048.f),
                   (_Float16)((v.y - (float)h[1]) * 2048.f),
                   (_Float16)((v.z - (float)h[2]) * 2048.f),
                   (_Float16)((v.w - (float)h[3]) * 2048.f)};
        reinterpret_cast<f16x4*>(xl)[i] = l;
    }
}

struct WSeg { const float* src; _Float16* dh; _Float16* dl; int K; int N; };
struct WSegs { WSeg s[8]; };

// dh/dl transposed planes: WT[n][k] = W[k][n]
__global__ void convert_wt_kernel(WSegs segs) {
    WSeg sg = segs.s[blockIdx.y];
    int i = blockIdx.x * 256 + threadIdx.x;
    if (i < sg.K * sg.N) {
        int n = i / sg.K, k = i - n * sg.K;
        float w = sg.src[(size_t)k * sg.N + n];
        _Float16 hi = (_Float16)w;
        sg.dh[i] = hi;
        sg.dl[i] = (_Float16)((w - (float)hi) * 2048.f);
    }
}

// --------------------- global->LDS 16B helper -------------------------------
// dst_wavebase must be wave-uniform; HW scatters lane i to dst+16*i.
__device__ __forceinline__ void gload_lds16(const _Float16* src, char* dst_wavebase) {
#if __has_builtin(__builtin_amdgcn_global_load_lds)
    __builtin_amdgcn_global_load_lds(
        (const __attribute__((address_space(1))) void*)src,
        (__attribute__((address_space(3))) void*)dst_wavebase, 16, 0, 0);
#else
    *reinterpret_cast<f16x8*>(dst_wavebase + (threadIdx.x & 63) * 16) =
        *reinterpret_cast<const f16x8*>(src);
#endif
}

// ---------------------------------------------------------------------------
// Split-fp16 MFMA GEMM, m97-style. 256 thr = 4 waves.
// LDS row (per A-row / B-col, per 32-k slab) = 8 chunks x 16B:
//   chunks 0-3 = hi plane k-octets, 4-7 = lo plane; chunk c stored at
//   physical slot c ^ (row&7)  -> frag ds_read_b128 2-way bank alias (free),
//   loader contiguous (global_load_lds forbids padding).
// Double-buffered slabs, prefetch issued before compute (overlap), one
// barrier per slab.
//   NN=192: ROWS=64;  wave w -> all rows, cols [w*48, +48)
//   NN=96 : ROWS=128; wave w -> rows [(w>>1)*64..), cols [(w&1)*48..)
// OM bit0: fp32 out Cf; bit1: fp16 planes out (Ch, Cl x2048). rowscale last.
// ---------------------------------------------------------------------------
template <int KK, int NN, int ACT, int OM>
__global__ __launch_bounds__(256, 2) void mfma_gemm(
    const _Float16* __restrict__ Ah, const _Float16* __restrict__ Al,
    const _Float16* __restrict__ WhT, const _Float16* __restrict__ WlT,
    const float* __restrict__ bias, const float* __restrict__ rowscale,
    float* __restrict__ Cf, _Float16* __restrict__ Ch, _Float16* __restrict__ Cl,
    int M) {
    constexpr int ROWS = (NN == 192) ? 64 : 128;
    constexpr int NS = KK / 32;                  // slabs
    constexpr int BUF = (ROWS + NN) * 128;       // bytes per buffer
    constexpr int A_IT = ROWS * 8 / 256;         // chunk-issues per thread
    constexpr int B_IT = NN * 8 / 256;
    __shared__ char smem[2 * BUF];

    const int tid = threadIdx.x;
    const int wave = tid >> 6, lane = tid & 63;
    const int quad = lane >> 4, l16 = lane & 15;
    const int m0 = (NN == 192) ? 0 : (wave >> 1) * 64;
    const int n0 = (NN == 192) ? wave * 48 : (wave & 1) * 48;
    const int row0 = blockIdx.x * ROWS;
    const size_t arow0 = (size_t)row0 * KK;
    const int wb = (tid & ~63) * 16;  // wave-uniform chunk-byte offset

    f32x4 acc[4][3], acc2[4][3];
#pragma unroll
    for (int mt = 0; mt < 4; ++mt)
#pragma unroll
        for (int nt = 0; nt < 3; ++nt) {
            acc[mt][nt] = (f32x4){0.f, 0.f, 0.f, 0.f};
            acc2[mt][nt] = (f32x4){0.f, 0.f, 0.f, 0.f};
        }

    auto stage = [&](char* buf, int ks) {
        char* Ab = buf;
        char* Bb = buf + ROWS * 128;
#pragma unroll
        for (int n = 0; n < A_IT; ++n) {
            int idx = n * 256 + tid;
            int r = idx >> 3, slot = idx & 7;
            int c = slot ^ (r & 7);
            const _Float16* src = (c < 4 ? Ah : Al) + arow0 + (size_t)r * KK + ks + (c & 3) * 8;
            gload_lds16(src, Ab + n * 4096 + wb);
        }
#pragma unroll
        for (int n = 0; n < B_IT; ++n) {
            int idx = n * 256 + tid;
            int r = idx >> 3, slot = idx & 7;
            int c = slot ^ (r & 7);
            const _Float16* src = (c < 4 ? WhT : WlT) + (size_t)r * KK + ks + (c & 3) * 8;
            gload_lds16(src, Bb + n * 4096 + wb);
        }
    };

    stage(smem, 0);
    __syncthreads();
#pragma unroll
    for (int i = 0; i < NS; ++i) {
        if (i + 1 < NS) stage(smem + ((i + 1) & 1) * BUF, (i + 1) * 32);
        const _Float16* As = (const _Float16*)(smem + (i & 1) * BUF);
        const _Float16* Bs = As + ROWS * 64;  // halves
        f16x8 ah[4], al[4], bh[3], bl[3];
#pragma unroll
        for (int mt = 0; mt < 4; ++mt) {
            int R = m0 + mt * 16 + l16;
            int ph = quad ^ (R & 7);
            ah[mt] = *reinterpret_cast<const f16x8*>(As + R * 64 + ph * 8);
            al[mt] = *reinterpret_cast<const f16x8*>(As + R * 64 + (ph ^ 4) * 8);
        }
#pragma unroll
        for (int nt = 0; nt < 3; ++nt) {
            int C = n0 + nt * 16 + l16;
            int ph = quad ^ (C & 7);
            bh[nt] = *reinterpret_cast<const f16x8*>(Bs + C * 64 + ph * 8);
            bl[nt] = *reinterpret_cast<const f16x8*>(Bs + C * 64 + (ph ^ 4) * 8);
        }
#pragma unroll
        for (int mt = 0; mt < 4; ++mt)
#pragma unroll
            for (int nt = 0; nt < 3; ++nt) {
                acc[mt][nt] = __builtin_amdgcn_mfma_f32_16x16x32_f16(ah[mt], bh[nt], acc[mt][nt], 0, 0, 0);
                acc2[mt][nt] = __builtin_amdgcn_mfma_f32_16x16x32_f16(ah[mt], bl[nt], acc2[mt][nt], 0, 0, 0);
                acc2[mt][nt] = __builtin_amdgcn_mfma_f32_16x16x32_f16(al[mt], bh[nt], acc2[mt][nt], 0, 0, 0);
            }
        __syncthreads();
    }

    // epilogue: C/D layout col=lane&15, row=quad*4+reg
    float bv[3];
#pragma unroll
    for (int nt = 0; nt < 3; ++nt) bv[nt] = bias ? bias[n0 + nt * 16 + l16] : 0.f;
#pragma unroll
    for (int mt = 0; mt < 4; ++mt)
#pragma unroll
        for (int i = 0; i < 4; ++i) {
            int row = row0 + m0 + mt * 16 + quad * 4 + i;
            if (row < M) {
                float rs = rowscale ? rowscale[row] : 1.f;
#pragma unroll
                for (int nt = 0; nt < 3; ++nt) {
                    int col = n0 + nt * 16 + l16;
                    float v = acc[mt][nt][i] + acc2[mt][nt][i] * (1.f / 2048.f) + bv[nt];
                    if (ACT == 1) v = fmaxf(v, 0.f);
                    v *= rs;
                    if (OM & 1) Cf[(size_t)row * NN + col] = v;
                    if (OM & 2) {
                        _Float16 hi = (_Float16)v;
                        Ch[(size_t)row * NN + col] = hi;
                        Cl[(size_t)row * NN + col] = (_Float16)((v - (float)hi) * 2048.f);
                    }
                }
            }
        }
}

// ---------------------------------------------------------------------------
// fp32 aggregation (round-3 design: whole rows, one wave per node, 94 us).
// h = h + relu(dinv[n]*(msc[n] + sum_e msc[src_e]) + B); h kept as fp16
// planes (hi + lo/2048), reconstructed/re-split in fp32 here.
// ---------------------------------------------------------------------------
__global__ __launch_bounds__(256) void aggregate_kernel(
    const float* __restrict__ msc, const int* __restrict__ csr,
    const int* __restrict__ rowptr, const float* __restrict__ dinv,
    const float* __restrict__ bias, _Float16* __restrict__ h_hi,
    _Float16* __restrict__ h_lo, int M) {
    int wid = (blockIdx.x * 256 + threadIdx.x) >> 6;
    int lane = threadIdx.x & 63;
    if (wid >= M || lane >= 48) return;
    const float4* base = reinterpret_cast<const float4*>(msc);
    float4 a = base[(size_t)wid * 48 + lane];  // self-loop (already * dinv[wid])
    float4 a2 = make_float4(0.f, 0.f, 0.f, 0.f);
    int beg = rowptr[wid], end = rowptr[wid + 1];
    int e = beg;
    for (; e + 1 < end; e += 2) {
        int s0 = csr[e], s1 = csr[e + 1];
        float4 v0 = base[(size_t)s0 * 48 + lane];
        float4 v1 = base[(size_t)s1 * 48 + lane];
        a.x += v0.x; a.y += v0.y; a.z += v0.z; a.w += v0.w;
        a2.x += v1.x; a2.y += v1.y; a2.z += v1.z; a2.w += v1.w;
    }
    if (e < end) {
        int s = csr[e];
        float4 v = base[(size_t)s * 48 + lane];
        a.x += v.x; a.y += v.y; a.z += v.z; a.w += v.w;
    }
    a.x += a2.x; a.y += a2.y; a.z += a2.z; a.w += a2.w;
    float dn = dinv[wid];
    float4 b = reinterpret_cast<const float4*>(bias)[lane];
    f16x4* hp = reinterpret_cast<f16x4*>(h_hi) + (size_t)wid * 48 + lane;
    f16x4* lp = reinterpret_cast<f16x4*>(h_lo) + (size_t)wid * 48 + lane;
    f16x4 hh = *hp, hl = *lp;
    float4 hv;
    hv.x = (float)hh[0] + (float)hl[0] * (1.f / 2048.f) + fmaxf(a.x * dn + b.x, 0.f);
    hv.y = (float)hh[1] + (float)hl[1] * (1.f / 2048.f) + fmaxf(a.y * dn + b.y, 0.f);
    hv.z = (float)hh[2] + (float)hl[2] * (1.f / 2048.f) + fmaxf(a.z * dn + b.z, 0.f);
    hv.w = (float)hh[3] + (float)hl[3] * (1.f / 2048.f) + fmaxf(a.w * dn + b.w, 0.f);
    f16x4 nh = {(_Float16)hv.x, (_Float16)hv.y, (_Float16)hv.z, (_Float16)hv.w};
    f16x4 nl = {(_Float16)((hv.x - (float)nh[0]) * 2048.f),
                (_Float16)((hv.y - (float)nh[1]) * 2048.f),
                (_Float16)((hv.z - (float)nh[2]) * 2048.f),
                (_Float16)((hv.w - (float)nh[3]) * 2048.f)};
    *hp = nh;
    *lp = nl;
}

// ---------------------------------------------------------------------------
// Tail: pos = p2@Wp3+bp3; rad = sigmoid(r@Wr2+br2); out = pos/(|pos|+1e-8)*rad
// ---------------------------------------------------------------------------
__global__ void finalize_kernel(const float* __restrict__ p2, const float* __restrict__ rbuf,
                                const float* __restrict__ Wp3, const float* __restrict__ bp3,
                                const float* __restrict__ Wr2, const float* __restrict__ br2,
                                float* __restrict__ out, int M) {
    int n = blockIdx.x * 256 + threadIdx.x;
    if (n >= M) return;
    const float4* p = reinterpret_cast<const float4*>(p2 + (size_t)n * 96);
    const float4* r = reinterpret_cast<const float4*>(rbuf + (size_t)n * 96);
    float a0 = 0.f, a1 = 0.f, rr = 0.f;
#pragma unroll
    for (int q = 0; q < 24; q++) {
        float4 pv = p[q];
        float4 rv = r[q];
        float4 w01 = reinterpret_cast<const float4*>(Wp3)[2 * q];
        float4 w23 = reinterpret_cast<const float4*>(Wp3)[2 * q + 1];
        a0 += pv.x * w01.x + pv.y * w01.z + pv.z * w23.x + pv.w * w23.z;
        a1 += pv.x * w01.y + pv.y * w01.w + pv.z * w23.y + pv.w * w23.w;
        float4 wr = reinterpret_cast<const float4*>(Wr2)[q];
        rr += rv.x * wr.x + rv.y * wr.y + rv.z * wr.z + rv.w * wr.w;
    }
    a0 += bp3[0];
    a1 += bp3[1];
    rr += br2[0];
    float radius = 1.f / (1.f + expf(-rr));
    float nrm = sqrtf(a0 * a0 + a1 * a1) + 1e-8f;
    float s = radius / nrm;
    out[(size_t)n * 2 + 0] = a0 * s;
    out[(size_t)n * 2 + 1] = a1 * s;
}

extern "C" void kernel_launch(void* const* d_in, const int* in_sizes, int n_in,
                              void* d_out, int out_size, void* d_ws, size_t ws_size,
                              hipStream_t stream) {
    const float* x     = (const float*)d_in[0];
    const int*   ei    = (const int*)d_in[1];
    const float* Wp    = (const float*)d_in[2];
    const float* bp    = (const float*)d_in[3];
    const float* convW = (const float*)d_in[4];
    const float* convB = (const float*)d_in[5];
    const float* Wp1   = (const float*)d_in[6];
    const float* bp1   = (const float*)d_in[7];
    const float* Wp2   = (const float*)d_in[8];
    const float* bp2   = (const float*)d_in[9];
    const float* Wp3   = (const float*)d_in[10];
    const float* bp3   = (const float*)d_in[11];
    const float* Wr1   = (const float*)d_in[12];
    const float* br1   = (const float*)d_in[13];
    const float* Wr2   = (const float*)d_in[14];
    const float* br2   = (const float*)d_in[15];
    float* out = (float*)d_out;

    const int M = in_sizes[0] / 128;  // 50000
    const int E = in_sizes[1] / 2;    // 800000
    const int* srcI = ei;
    const int* dstI = ei + E;

    char* w = (char*)d_ws;
    size_t off = 0;
    auto alloc = [&](size_t b) { size_t o = off; off += (b + 255) & ~(size_t)255; return o; };
    float*    msc  = (float*)(w + alloc((size_t)M * 192 * 4));
    _Float16* h_hi = (_Float16*)(w + alloc((size_t)M * 192 * 2));
    _Float16* h_lo = (_Float16*)(w + alloc((size_t)M * 192 * 2));
    char*     xreg = w + alloc((size_t)M * 128 * 2 * 2);  // xh+xl; later p2 fp32
    float*    rb   = (float*)(w + alloc((size_t)M * 96 * 4));
    _Float16* WphT  = (_Float16*)(w + alloc((size_t)128 * 192 * 2));
    _Float16* WplT  = (_Float16*)(w + alloc((size_t)128 * 192 * 2));
    _Float16* cWhT  = (_Float16*)(w + alloc((size_t)4 * 192 * 192 * 2));
    _Float16* cWlT  = (_Float16*)(w + alloc((size_t)4 * 192 * 192 * 2));
    _Float16* Wp1hT = (_Float16*)(w + alloc((size_t)192 * 192 * 2));
    _Float16* Wp1lT = (_Float16*)(w + alloc((size_t)192 * 192 * 2));
    _Float16* Wp2hT = (_Float16*)(w + alloc((size_t)96 * 192 * 2));
    _Float16* Wp2lT = (_Float16*)(w + alloc((size_t)96 * 192 * 2));
    _Float16* Wr1hT = (_Float16*)(w + alloc((size_t)96 * 192 * 2));
    _Float16* Wr1lT = (_Float16*)(w + alloc((size_t)96 * 192 * 2));
    int*      cnt    = (int*)(w + alloc((size_t)M * 4));
    float*    dinv   = (float*)(w + alloc((size_t)M * 4));
    int*      rowptr = (int*)(w + alloc((size_t)(M + 1) * 4));
    int*      cursor = (int*)(w + alloc((size_t)M * 4));
    int*      csr    = (int*)(w + alloc((size_t)E * 4));
    int*      bsum   = (int*)(w + alloc(256 * 4));
    int*      boff   = (int*)(w + alloc(256 * 4));

    _Float16* xh  = (_Float16*)xreg;
    _Float16* xl  = xh + (size_t)M * 128;
    float*    p2  = (float*)xreg;           // alias: x planes dead after proj
    _Float16* p1h = (_Float16*)msc;         // alias: msc dead after last aggregate
    _Float16* p1l = p1h + (size_t)M * 192;

    hipMemsetAsync(cnt, 0, (size_t)M * 4, stream);
    hipMemsetAsync(cursor, 0, (size_t)M * 4, stream);

    // graph setup
    count_kernel<<<(E + 255) / 256, 256, 0, stream>>>(dstI, E, cnt);
    int nb = (M + 255) / 256;
    scan1_kernel<<<nb, 256, 0, stream>>>(cnt, M, rowptr, bsum, dinv);
    scan2_kernel<<<1, 256, 0, stream>>>(bsum, nb, boff);
    scan3_kernel<<<(M + 256) / 256, 256, 0, stream>>>(rowptr, M, E, boff);
    fill_kernel<<<(E + 255) / 256, 256, 0, stream>>>(srcI, dstI, E, rowptr, cursor, csr);

    // conversions
    convert_x_kernel<<<((M * 128 / 4) + 255) / 256, 256, 0, stream>>>(x, xh, xl, M * 128 / 4);
    WSegs segs;
    segs.s[0] = {Wp, WphT, WplT, 128, 192};
    segs.s[1] = {convW + 0 * 192 * 192, cWhT + 0 * 192 * 192, cWlT + 0 * 192 * 192, 192, 192};
    segs.s[2] = {convW + 1 * 192 * 192, cWhT + 1 * 192 * 192, cWlT + 1 * 192 * 192, 192, 192};
    segs.s[3] = {convW + 2 * 192 * 192, cWhT + 2 * 192 * 192, cWlT + 2 * 192 * 192, 192, 192};
    segs.s[4] = {convW + 3 * 192 * 192, cWhT + 3 * 192 * 192, cWlT + 3 * 192 * 192, 192, 192};
    segs.s[5] = {Wp1, Wp1hT, Wp1lT, 192, 192};
    segs.s[6] = {Wp2, Wp2hT, Wp2lT, 192, 96};
    segs.s[7] = {Wr1, Wr1hT, Wr1lT, 192, 96};
    convert_wt_kernel<<<dim3(144, 8), 256, 0, stream>>>(segs);

    const int gb192 = (M + 63) / 64;    // 782 (ROWS=64)
    const int gb96  = (M + 127) / 128;  // 391 (ROWS=128)

    // h = x @ Wp + bp -> planes
    mfma_gemm<128, 192, 0, 2><<<gb192, 256, 0, stream>>>(
        xh, xl, WphT, WplT, bp, nullptr, nullptr, h_hi, h_lo, M);
    // 4 GCN layers
    for (int i = 0; i < 4; i++) {
        mfma_gemm<192, 192, 0, 1><<<gb192, 256, 0, stream>>>(
            h_hi, h_lo, cWhT + (size_t)i * 192 * 192, cWlT + (size_t)i * 192 * 192,
            nullptr, dinv, msc, nullptr, nullptr, M);
        aggregate_kernel<<<(M + 3) / 4, 256, 0, stream>>>(
            msc, csr, rowptr, dinv, convB + (size_t)i * 192, h_hi, h_lo, M);
    }
    // heads
    mfma_gemm<192, 192, 1, 2><<<gb192, 256, 0, stream>>>(
        h_hi, h_lo, Wp1hT, Wp1lT, bp1, nullptr, nullptr, p1h, p1l, M);
    mfma_gemm<192, 96, 1, 1><<<gb96, 256, 0, stream>>>(
        p1h, p1l, Wp2hT, Wp2lT, bp2, nullptr, p2, nullptr, nullptr, M);
    mfma_gemm<192, 96, 1, 1><<<gb96, 256, 0, stream>>>(
        h_hi, h_lo, Wr1hT, Wr1lT, br1, nullptr, rb, nullptr, nullptr, M);
    finalize_kernel<<<(M + 255) / 256, 256, 0, stream>>>(p2, rb, Wp3, bp3, Wr2, br2, out, M);
}

// Round 6
// 751.074 us; speedup vs baseline: 1.7757x; 1.0203x over previous
//
#include <hip/hip_runtime.h>
#include <math.h>

typedef __attribute__((ext_vector_type(8))) _Float16 f16x8;
typedef __attribute__((ext_vector_type(4))) _Float16 f16x4;
typedef __attribute__((ext_vector_type(4))) float f32x4;

// ---------------------------------------------------------------------------
// Precision: split-fp16 planes a = ah + al/2048 (al stored x2048).
// C = ah@wh + (ah@wl_s + al_s@wh)/2048 -> ~2^-22 rel. Budget is ~2^-20 rel:
// rounds 1/3/5 show fp32-grade compute already gives absmax ~1-2e-3 vs
// threshold 1.9e-2 (worst-node amplification ~1e4 through pos/|pos|).
// => NO compression anywhere in the backbone; aggregation stays fp32.
// GEMM (round 6): A-only LDS dbuf via global_load_lds (8 KB), B pre-packed
// frag-major read straight from global (L1/L2-hot), ROWS=32, 4 blocks/CU.
// ---------------------------------------------------------------------------

// ------------------------- graph setup -------------------------------------
__global__ void count_kernel(const int* __restrict__ dst, int E, int* __restrict__ cnt) {
    int i = blockIdx.x * blockDim.x + threadIdx.x;
    if (i < E) atomicAdd(&cnt[dst[i]], 1);
}

__global__ void scan1_kernel(const int* __restrict__ cnt, int M,
                             int* __restrict__ rowptr, int* __restrict__ bsum,
                             float* __restrict__ dinv) {
    __shared__ int s[256];
    int t = threadIdx.x;
    int i = blockIdx.x * 256 + t;
    int v = (i < M) ? cnt[i] : 0;
    s[t] = v; __syncthreads();
    for (int o = 1; o < 256; o <<= 1) {
        int x = (t >= o) ? s[t - o] : 0;
        __syncthreads();
        s[t] += x;
        __syncthreads();
    }
    if (i < M) {
        rowptr[i] = s[t] - v;
        dinv[i] = rsqrtf((float)v + 1.0f);  // deg = in-deg + self-loop
    }
    if (t == 255) bsum[blockIdx.x] = s[255];
}

__global__ void scan2_kernel(const int* __restrict__ bsum, int nb, int* __restrict__ boff) {
    __shared__ int s[256];
    int t = threadIdx.x;
    int v = (t < nb) ? bsum[t] : 0;
    s[t] = v; __syncthreads();
    for (int o = 1; o < 256; o <<= 1) {
        int x = (t >= o) ? s[t - o] : 0;
        __syncthreads();
        s[t] += x;
        __syncthreads();
    }
    if (t < nb) boff[t] = s[t] - v;
}

__global__ void scan3_kernel(int* __restrict__ rowptr, int M, int E, const int* __restrict__ boff) {
    int i = blockIdx.x * 256 + threadIdx.x;
    if (i < M) rowptr[i] += boff[blockIdx.x];
    if (i == M) rowptr[M] = E;
}

__global__ void fill_kernel(const int* __restrict__ src, const int* __restrict__ dst, int E,
                            const int* __restrict__ rowptr, int* __restrict__ cursor,
                            int* __restrict__ csr) {
    int i = blockIdx.x * blockDim.x + threadIdx.x;
    if (i < E) {
        int d = dst[i];
        int slot = atomicAdd(&cursor[d], 1);
        csr[rowptr[d] + slot] = src[i];
    }
}

// ------------------------- converters --------------------------------------
__global__ void convert_x_kernel(const float* __restrict__ x, _Float16* __restrict__ xh,
                                 _Float16* __restrict__ xl, int n4) {
    int i = blockIdx.x * 256 + threadIdx.x;
    if (i < n4) {
        float4 v = reinterpret_cast<const float4*>(x)[i];
        f16x4 h = {(_Float16)v.x, (_Float16)v.y, (_Float16)v.z, (_Float16)v.w};
        reinterpret_cast<f16x4*>(xh)[i] = h;
        f16x4 l = {(_Float16)((v.x - (float)h[0]) * 2048.f),
                   (_Float16)((v.y - (float)h[1]) * 2048.f),
                   (_Float16)((v.z - (float)h[2]) * 2048.f),
                   (_Float16)((v.w - (float)h[3]) * 2048.f)};
        reinterpret_cast<f16x4*>(xl)[i] = l;
    }
}

// Frag-major B packing: for slab s (32 k), col-group g (16 cols), lane l
// (quad=l>>4, l16=l&15), 8 fp16 = col (g*16+l16), k = s*32+quad*8 .. +8.
// Flat index i = ((s*G + g)*64 + l)*8 + j, G = N/16. A wave's b-frag load is
// then 64 lanes x contiguous 16 B = 1 KB contiguous -> L1-friendly.
struct WSeg { const float* src; _Float16* dh; _Float16* dl; int K; int N; };
struct WSegs { WSeg s[8]; };

__global__ void pack_b_kernel(WSegs segs) {
    WSeg sg = segs.s[blockIdx.y];
    int i = blockIdx.x * 256 + threadIdx.x;
    int total = sg.K * sg.N;
    if (i >= total) return;
    int G = sg.N >> 4;
    int s = i / (G * 512);
    int r = i - s * (G * 512);
    int g = r >> 9;
    int r2 = r & 511;
    int l = r2 >> 3, j = r2 & 7;
    int n = g * 16 + (l & 15);
    int k = s * 32 + (l >> 4) * 8 + j;
    float w = sg.src[(size_t)k * sg.N + n];
    _Float16 hi = (_Float16)w;
    sg.dh[i] = hi;
    sg.dl[i] = (_Float16)((w - (float)hi) * 2048.f);
}

// --------------------- global->LDS 16B helper -------------------------------
// dst_wavebase must be wave-uniform; HW scatters lane i to dst+16*i.
__device__ __forceinline__ void gload_lds16(const _Float16* src, char* dst_wavebase) {
#if __has_builtin(__builtin_amdgcn_global_load_lds)
    __builtin_amdgcn_global_load_lds(
        (const __attribute__((address_space(1))) void*)src,
        (__attribute__((address_space(3))) void*)dst_wavebase, 16, 0, 0);
#else
    *reinterpret_cast<f16x8*>(dst_wavebase + (threadIdx.x & 63) * 16) =
        *reinterpret_cast<const f16x8*>(src);
#endif
}

// ---------------------------------------------------------------------------
// Split-fp16 MFMA GEMM, A-LDS/B-direct hybrid. 256 thr = 4 waves, ROWS=32.
// A slab (32 rows x 32 k x 2 planes = 4 KB) staged via global_load_lds,
// double-buffered (8 KB LDS total). LDS row = 8 x 16B chunks (4 hi + 4 lo),
// chunk c at slot c^(row&7): loader contiguous, frag ds_read_b128 spreads
// across banks (2-way alias only = free).
// B read per-slab straight from frag-major packed global arrays (1 KB
// contiguous per frag; hot in L1/L2 since every block reads the same 147 KB).
// Loop is barrier-first: the barrier drains the prefetch issued LAST iter
// (full compute phase of flight time); ~4 blocks/CU hide the rest.
//   NN=192: waves share rows 0-31 (2 m-tiles), wave w -> cols [w*48, +48)
//   NN=96 : wave w -> rows [(w>>1)*16, +16) (1 m-tile), cols [(w&1)*48, +48)
// OM bit0: fp32 out Cf; bit1: fp16 planes out (Ch, Cl x2048). rowscale last.
// ---------------------------------------------------------------------------
template <int KK, int NN, int ACT, int OM>
__global__ __launch_bounds__(256, 4) void mfma_gemm(
    const _Float16* __restrict__ Ah, const _Float16* __restrict__ Al,
    const _Float16* __restrict__ Bph, const _Float16* __restrict__ Bpl,
    const float* __restrict__ bias, const float* __restrict__ rowscale,
    float* __restrict__ Cf, _Float16* __restrict__ Ch, _Float16* __restrict__ Cl,
    int M) {
    constexpr int ROWS = 32;
    constexpr int NS = KK / 32;
    constexpr int MT = (NN == 192) ? 2 : 1;
    constexpr int G = NN / 16;
    __shared__ char smem[2 * 4096];

    const int tid = threadIdx.x;
    const int wave = tid >> 6, lane = tid & 63;
    const int quad = lane >> 4, l16 = lane & 15;
    const int m0 = (NN == 192) ? 0 : (wave >> 1) * 16;
    const int n0 = (NN == 192) ? wave * 48 : (wave & 1) * 48;
    const int g0 = n0 >> 4;
    const int row0 = blockIdx.x * ROWS;
    const size_t arow0 = (size_t)row0 * KK;
    const int wb = (tid & ~63) * 16;  // wave-uniform LDS chunk base

    f32x4 acc[MT][3], acc2[MT][3];
#pragma unroll
    for (int mt = 0; mt < MT; ++mt)
#pragma unroll
        for (int nt = 0; nt < 3; ++nt) {
            acc[mt][nt] = (f32x4){0.f, 0.f, 0.f, 0.f};
            acc2[mt][nt] = (f32x4){0.f, 0.f, 0.f, 0.f};
        }

    // one 16B chunk per thread per slab: chunk idx = tid; row r = tid>>3,
    // slot = tid&7, logical chunk c = slot^(r&7): c<4 -> hi octet c, else lo.
    auto stageA = [&](char* buf, int ks) {
        int r = tid >> 3, slot = tid & 7;
        int c = slot ^ (r & 7);
        const _Float16* src = (c < 4 ? Ah : Al) + arow0 + (size_t)r * KK + ks + (c & 3) * 8;
        gload_lds16(src, buf + wb);
    };

    stageA(smem, 0);
#pragma unroll
    for (int s = 0; s < NS; ++s) {
        __syncthreads();  // drains prefetch issued last iter (or pre-loop)
        if (s + 1 < NS) stageA(smem + ((s + 1) & 1) * 4096, (s + 1) * 32);

        f16x8 bh[3], bl[3];
#pragma unroll
        for (int nt = 0; nt < 3; ++nt) {
            size_t o = ((size_t)(s * G + g0 + nt) * 64 + lane) * 8;
            bh[nt] = *reinterpret_cast<const f16x8*>(Bph + o);
            bl[nt] = *reinterpret_cast<const f16x8*>(Bpl + o);
        }
        const _Float16* As = (const _Float16*)(smem + (s & 1) * 4096);
        f16x8 ah[MT], al[MT];
#pragma unroll
        for (int mt = 0; mt < MT; ++mt) {
            int R = m0 + mt * 16 + l16;
            int ph = quad ^ (R & 7);
            ah[mt] = *reinterpret_cast<const f16x8*>(As + R * 64 + ph * 8);
            al[mt] = *reinterpret_cast<const f16x8*>(As + R * 64 + (ph ^ 4) * 8);
        }
#pragma unroll
        for (int mt = 0; mt < MT; ++mt)
#pragma unroll
            for (int nt = 0; nt < 3; ++nt) {
                acc[mt][nt] = __builtin_amdgcn_mfma_f32_16x16x32_f16(ah[mt], bh[nt], acc[mt][nt], 0, 0, 0);
                acc2[mt][nt] = __builtin_amdgcn_mfma_f32_16x16x32_f16(ah[mt], bl[nt], acc2[mt][nt], 0, 0, 0);
                acc2[mt][nt] = __builtin_amdgcn_mfma_f32_16x16x32_f16(al[mt], bh[nt], acc2[mt][nt], 0, 0, 0);
            }
    }

    // epilogue: C/D layout col=lane&15, row=quad*4+reg
    float bv[3];
#pragma unroll
    for (int nt = 0; nt < 3; ++nt) bv[nt] = bias ? bias[n0 + nt * 16 + l16] : 0.f;
#pragma unroll
    for (int mt = 0; mt < MT; ++mt)
#pragma unroll
        for (int i = 0; i < 4; ++i) {
            int row = row0 + m0 + mt * 16 + quad * 4 + i;
            if (row < M) {
                float rs = rowscale ? rowscale[row] : 1.f;
#pragma unroll
                for (int nt = 0; nt < 3; ++nt) {
                    int col = n0 + nt * 16 + l16;
                    float v = acc[mt][nt][i] + acc2[mt][nt][i] * (1.f / 2048.f) + bv[nt];
                    if (ACT == 1) v = fmaxf(v, 0.f);
                    v *= rs;
                    if (OM & 1) Cf[(size_t)row * NN + col] = v;
                    if (OM & 2) {
                        _Float16 hi = (_Float16)v;
                        Ch[(size_t)row * NN + col] = hi;
                        Cl[(size_t)row * NN + col] = (_Float16)((v - (float)hi) * 2048.f);
                    }
                }
            }
        }
}

// ---------------------------------------------------------------------------
// fp32 aggregation (round-3 design, at its LLC random-gather bound ~94 us).
// h = h + relu(dinv[n]*(msc[n] + sum_e msc[src_e]) + B); h kept as fp16
// planes (hi + lo/2048), reconstructed/re-split in fp32 here.
// ---------------------------------------------------------------------------
__global__ __launch_bounds__(256) void aggregate_kernel(
    const float* __restrict__ msc, const int* __restrict__ csr,
    const int* __restrict__ rowptr, const float* __restrict__ dinv,
    const float* __restrict__ bias, _Float16* __restrict__ h_hi,
    _Float16* __restrict__ h_lo, int M) {
    int wid = (blockIdx.x * 256 + threadIdx.x) >> 6;
    int lane = threadIdx.x & 63;
    if (wid >= M || lane >= 48) return;
    const float4* base = reinterpret_cast<const float4*>(msc);
    float4 a = base[(size_t)wid * 48 + lane];  // self-loop (already * dinv[wid])
    float4 a2 = make_float4(0.f, 0.f, 0.f, 0.f);
    int beg = rowptr[wid], end = rowptr[wid + 1];
    int e = beg;
    for (; e + 1 < end; e += 2) {
        int s0 = csr[e], s1 = csr[e + 1];
        float4 v0 = base[(size_t)s0 * 48 + lane];
        float4 v1 = base[(size_t)s1 * 48 + lane];
        a.x += v0.x; a.y += v0.y; a.z += v0.z; a.w += v0.w;
        a2.x += v1.x; a2.y += v1.y; a2.z += v1.z; a2.w += v1.w;
    }
    if (e < end) {
        int s = csr[e];
        float4 v = base[(size_t)s * 48 + lane];
        a.x += v.x; a.y += v.y; a.z += v.z; a.w += v.w;
    }
    a.x += a2.x; a.y += a2.y; a.z += a2.z; a.w += a2.w;
    float dn = dinv[wid];
    float4 b = reinterpret_cast<const float4*>(bias)[lane];
    f16x4* hp = reinterpret_cast<f16x4*>(h_hi) + (size_t)wid * 48 + lane;
    f16x4* lp = reinterpret_cast<f16x4*>(h_lo) + (size_t)wid * 48 + lane;
    f16x4 hh = *hp, hl = *lp;
    float4 hv;
    hv.x = (float)hh[0] + (float)hl[0] * (1.f / 2048.f) + fmaxf(a.x * dn + b.x, 0.f);
    hv.y = (float)hh[1] + (float)hl[1] * (1.f / 2048.f) + fmaxf(a.y * dn + b.y, 0.f);
    hv.z = (float)hh[2] + (float)hl[2] * (1.f / 2048.f) + fmaxf(a.z * dn + b.z, 0.f);
    hv.w = (float)hh[3] + (float)hl[3] * (1.f / 2048.f) + fmaxf(a.w * dn + b.w, 0.f);
    f16x4 nh = {(_Float16)hv.x, (_Float16)hv.y, (_Float16)hv.z, (_Float16)hv.w};
    f16x4 nl = {(_Float16)((hv.x - (float)nh[0]) * 2048.f),
                (_Float16)((hv.y - (float)nh[1]) * 2048.f),
                (_Float16)((hv.z - (float)nh[2]) * 2048.f),
                (_Float16)((hv.w - (float)nh[3]) * 2048.f)};
    *hp = nh;
    *lp = nl;
}

// ---------------------------------------------------------------------------
// Tail: pos = p2@Wp3+bp3; rad = sigmoid(r@Wr2+br2); out = pos/(|pos|+1e-8)*rad
// ---------------------------------------------------------------------------
__global__ void finalize_kernel(const float* __restrict__ p2, const float* __restrict__ rbuf,
                                const float* __restrict__ Wp3, const float* __restrict__ bp3,
                                const float* __restrict__ Wr2, const float* __restrict__ br2,
                                float* __restrict__ out, int M) {
    int n = blockIdx.x * 256 + threadIdx.x;
    if (n >= M) return;
    const float4* p = reinterpret_cast<const float4*>(p2 + (size_t)n * 96);
    const float4* r = reinterpret_cast<const float4*>(rbuf + (size_t)n * 96);
    float a0 = 0.f, a1 = 0.f, rr = 0.f;
#pragma unroll
    for (int q = 0; q < 24; q++) {
        float4 pv = p[q];
        float4 rv = r[q];
        float4 w01 = reinterpret_cast<const float4*>(Wp3)[2 * q];
        float4 w23 = reinterpret_cast<const float4*>(Wp3)[2 * q + 1];
        a0 += pv.x * w01.x + pv.y * w01.z + pv.z * w23.x + pv.w * w23.z;
        a1 += pv.x * w01.y + pv.y * w01.w + pv.z * w23.y + pv.w * w23.w;
        float4 wr = reinterpret_cast<const float4*>(Wr2)[q];
        rr += rv.x * wr.x + rv.y * wr.y + rv.z * wr.z + rv.w * wr.w;
    }
    a0 += bp3[0];
    a1 += bp3[1];
    rr += br2[0];
    float radius = 1.f / (1.f + expf(-rr));
    float nrm = sqrtf(a0 * a0 + a1 * a1) + 1e-8f;
    float s = radius / nrm;
    out[(size_t)n * 2 + 0] = a0 * s;
    out[(size_t)n * 2 + 1] = a1 * s;
}

extern "C" void kernel_launch(void* const* d_in, const int* in_sizes, int n_in,
                              void* d_out, int out_size, void* d_ws, size_t ws_size,
                              hipStream_t stream) {
    const float* x     = (const float*)d_in[0];
    const int*   ei    = (const int*)d_in[1];
    const float* Wp    = (const float*)d_in[2];
    const float* bp    = (const float*)d_in[3];
    const float* convW = (const float*)d_in[4];
    const float* convB = (const float*)d_in[5];
    const float* Wp1   = (const float*)d_in[6];
    const float* bp1   = (const float*)d_in[7];
    const float* Wp2   = (const float*)d_in[8];
    const float* bp2   = (const float*)d_in[9];
    const float* Wp3   = (const float*)d_in[10];
    const float* bp3   = (const float*)d_in[11];
    const float* Wr1   = (const float*)d_in[12];
    const float* br1   = (const float*)d_in[13];
    const float* Wr2   = (const float*)d_in[14];
    const float* br2   = (const float*)d_in[15];
    float* out = (float*)d_out;

    const int M = in_sizes[0] / 128;  // 50000
    const int E = in_sizes[1] / 2;    // 800000
    const int* srcI = ei;
    const int* dstI = ei + E;

    char* w = (char*)d_ws;
    size_t off = 0;
    auto alloc = [&](size_t b) { size_t o = off; off += (b + 255) & ~(size_t)255; return o; };
    float*    msc  = (float*)(w + alloc((size_t)M * 192 * 4));
    _Float16* h_hi = (_Float16*)(w + alloc((size_t)M * 192 * 2));
    _Float16* h_lo = (_Float16*)(w + alloc((size_t)M * 192 * 2));
    char*     xreg = w + alloc((size_t)M * 128 * 2 * 2);  // xh+xl; later p2 fp32
    float*    rb   = (float*)(w + alloc((size_t)M * 96 * 4));
    _Float16* WpPh  = (_Float16*)(w + alloc((size_t)128 * 192 * 2));
    _Float16* WpPl  = (_Float16*)(w + alloc((size_t)128 * 192 * 2));
    _Float16* cWPh  = (_Float16*)(w + alloc((size_t)4 * 192 * 192 * 2));
    _Float16* cWPl  = (_Float16*)(w + alloc((size_t)4 * 192 * 192 * 2));
    _Float16* Wp1Ph = (_Float16*)(w + alloc((size_t)192 * 192 * 2));
    _Float16* Wp1Pl = (_Float16*)(w + alloc((size_t)192 * 192 * 2));
    _Float16* Wp2Ph = (_Float16*)(w + alloc((size_t)192 * 96 * 2));
    _Float16* Wp2Pl = (_Float16*)(w + alloc((size_t)192 * 96 * 2));
    _Float16* Wr1Ph = (_Float16*)(w + alloc((size_t)192 * 96 * 2));
    _Float16* Wr1Pl = (_Float16*)(w + alloc((size_t)192 * 96 * 2));
    int*      cnt    = (int*)(w + alloc((size_t)M * 4));
    float*    dinv   = (float*)(w + alloc((size_t)M * 4));
    int*      rowptr = (int*)(w + alloc((size_t)(M + 1) * 4));
    int*      cursor = (int*)(w + alloc((size_t)M * 4));
    int*      csr    = (int*)(w + alloc((size_t)E * 4));
    int*      bsum   = (int*)(w + alloc(256 * 4));
    int*      boff   = (int*)(w + alloc(256 * 4));

    _Float16* xh  = (_Float16*)xreg;
    _Float16* xl  = xh + (size_t)M * 128;
    float*    p2  = (float*)xreg;           // alias: x planes dead after proj
    _Float16* p1h = (_Float16*)msc;         // alias: msc dead after last aggregate
    _Float16* p1l = p1h + (size_t)M * 192;

    hipMemsetAsync(cnt, 0, (size_t)M * 4, stream);
    hipMemsetAsync(cursor, 0, (size_t)M * 4, stream);

    // graph setup
    count_kernel<<<(E + 255) / 256, 256, 0, stream>>>(dstI, E, cnt);
    int nb = (M + 255) / 256;
    scan1_kernel<<<nb, 256, 0, stream>>>(cnt, M, rowptr, bsum, dinv);
    scan2_kernel<<<1, 256, 0, stream>>>(bsum, nb, boff);
    scan3_kernel<<<(M + 256) / 256, 256, 0, stream>>>(rowptr, M, E, boff);
    fill_kernel<<<(E + 255) / 256, 256, 0, stream>>>(srcI, dstI, E, rowptr, cursor, csr);

    // conversions
    convert_x_kernel<<<((M * 128 / 4) + 255) / 256, 256, 0, stream>>>(x, xh, xl, M * 128 / 4);
    WSegs segs;
    segs.s[0] = {Wp, WpPh, WpPl, 128, 192};
    segs.s[1] = {convW + 0 * 192 * 192, cWPh + 0 * 192 * 192, cWPl + 0 * 192 * 192, 192, 192};
    segs.s[2] = {convW + 1 * 192 * 192, cWPh + 1 * 192 * 192, cWPl + 1 * 192 * 192, 192, 192};
    segs.s[3] = {convW + 2 * 192 * 192, cWPh + 2 * 192 * 192, cWPl + 2 * 192 * 192, 192, 192};
    segs.s[4] = {convW + 3 * 192 * 192, cWPh + 3 * 192 * 192, cWPl + 3 * 192 * 192, 192, 192};
    segs.s[5] = {Wp1, Wp1Ph, Wp1Pl, 192, 192};
    segs.s[6] = {Wp2, Wp2Ph, Wp2Pl, 192, 96};
    segs.s[7] = {Wr1, Wr1Ph, Wr1Pl, 192, 96};
    pack_b_kernel<<<dim3(144, 8), 256, 0, stream>>>(segs);

    const int gb = (M + 31) / 32;  // 1563 blocks, 32 rows each (all GEMMs)

    // h = x @ Wp + bp -> planes
    mfma_gemm<128, 192, 0, 2><<<gb, 256, 0, stream>>>(
        xh, xl, WpPh, WpPl, bp, nullptr, nullptr, h_hi, h_lo, M);
    // 4 GCN layers
    for (int i = 0; i < 4; i++) {
        mfma_gemm<192, 192, 0, 1><<<gb, 256, 0, stream>>>(
            h_hi, h_lo, cWPh + (size_t)i * 192 * 192, cWPl + (size_t)i * 192 * 192,
            nullptr, dinv, msc, nullptr, nullptr, M);
        aggregate_kernel<<<(M + 3) / 4, 256, 0, stream>>>(
            msc, csr, rowptr, dinv, convB + (size_t)i * 192, h_hi, h_lo, M);
    }
    // heads
    mfma_gemm<192, 192, 1, 2><<<gb, 256, 0, stream>>>(
        h_hi, h_lo, Wp1Ph, Wp1Pl, bp1, nullptr, nullptr, p1h, p1l, M);
    mfma_gemm<192, 96, 1, 1><<<gb, 256, 0, stream>>>(
        p1h, p1l, Wp2Ph, Wp2Pl, bp2, nullptr, p2, nullptr, nullptr, M);
    mfma_gemm<192, 96, 1, 1><<<gb, 256, 0, stream>>>(
        h_hi, h_lo, Wr1Ph, Wr1Pl, br1, nullptr, rb, nullptr, nullptr, M);
    finalize_kernel<<<(M + 255) / 256, 256, 0, stream>>>(p2, rb, Wp3, bp3, Wr2, br2, out, M);
}

// Round 7
// 747.464 us; speedup vs baseline: 1.7842x; 1.0048x over previous
//
#include <hip/hip_runtime.h>
#include <math.h>

typedef __attribute__((ext_vector_type(8))) _Float16 f16x8;
typedef __attribute__((ext_vector_type(4))) _Float16 f16x4;
typedef __attribute__((ext_vector_type(4))) float f32x4;

// ---------------------------------------------------------------------------
// Precision: split-fp16 planes a = ah + al/2048 (al stored x2048).
// C = ah@wh + (ah@wl_s + al_s@wh)/2048 -> ~2^-22 rel (fp32-grade); the final
// pos/(|pos|+1e-8) amplifies error ~1e4 -> budget ~2^-20, no compression.
//
// Round 7 GEMM: stage the block's ENTIRE A-tile (NS x 4 KB <= 24 KB) via
// contiguous global_load_lds at kernel start, ONE __syncthreads, then a
// barrier-free K-loop (LDS frags + L2-hot frag-major B loads). Kills the
// per-slab vmcnt(0) drains that bounded rounds 3/5/6 (~40 us/GEMM).
//
// Packed activation layout (x, h, p1), "block-packed split-fp16":
//   rowblock rb = 32 rows, slab s = 32 k; page(rb,s) = 4 KB:
//   chunk16B(r, p) at ((rb*NS+s)*32 + r)*128 + p*16,
//   p = c ^ (r&7); c<4: hi-plane k-octet c; c>=4: lo-plane octet c-4.
//   Global image == LDS image (XOR baked in): staging is a pure memcpy;
//   frag ds_read_b128 banks spread (2-way alias = free).
// ---------------------------------------------------------------------------

// ------------------------- graph setup -------------------------------------
__global__ void count_kernel(const int* __restrict__ dst, int E, int* __restrict__ cnt) {
    int i = blockIdx.x * blockDim.x + threadIdx.x;
    if (i < E) atomicAdd(&cnt[dst[i]], 1);
}

__global__ void scan1_kernel(const int* __restrict__ cnt, int M,
                             int* __restrict__ rowptr, int* __restrict__ bsum,
                             float* __restrict__ dinv) {
    __shared__ int s[256];
    int t = threadIdx.x;
    int i = blockIdx.x * 256 + t;
    int v = (i < M) ? cnt[i] : 0;
    s[t] = v; __syncthreads();
    for (int o = 1; o < 256; o <<= 1) {
        int x = (t >= o) ? s[t - o] : 0;
        __syncthreads();
        s[t] += x;
        __syncthreads();
    }
    if (i < M) {
        rowptr[i] = s[t] - v;
        dinv[i] = rsqrtf((float)v + 1.0f);  // deg = in-deg + self-loop
    }
    if (t == 255) bsum[blockIdx.x] = s[255];
}

__global__ void scan2_kernel(const int* __restrict__ bsum, int nb, int* __restrict__ boff) {
    __shared__ int s[256];
    int t = threadIdx.x;
    int v = (t < nb) ? bsum[t] : 0;
    s[t] = v; __syncthreads();
    for (int o = 1; o < 256; o <<= 1) {
        int x = (t >= o) ? s[t - o] : 0;
        __syncthreads();
        s[t] += x;
        __syncthreads();
    }
    if (t < nb) boff[t] = s[t] - v;
}

__global__ void scan3_kernel(int* __restrict__ rowptr, int M, int E, const int* __restrict__ boff) {
    int i = blockIdx.x * 256 + threadIdx.x;
    if (i < M) rowptr[i] += boff[blockIdx.x];
    if (i == M) rowptr[M] = E;
}

__global__ void fill_kernel(const int* __restrict__ src, const int* __restrict__ dst, int E,
                            const int* __restrict__ rowptr, int* __restrict__ cursor,
                            int* __restrict__ csr) {
    int i = blockIdx.x * blockDim.x + threadIdx.x;
    if (i < E) {
        int d = dst[i];
        int slot = atomicAdd(&cursor[d], 1);
        csr[rowptr[d] + slot] = src[i];
    }
}

// ------------------------- converters --------------------------------------
// x -> block-packed split planes (NSX=4 slabs). One 16-B chunk per thread.
__global__ void convert_x_kernel(const float* __restrict__ x, _Float16* __restrict__ xp,
                                 int M, int nchunks) {
    int g = blockIdx.x * 256 + threadIdx.x;
    if (g >= nchunks) return;
    int p = g & 7;
    int t1 = g >> 3;
    int r = t1 & 31;
    int t2 = t1 >> 5;
    int s = t2 & 3;
    int rb = t2 >> 2;
    int c = p ^ (r & 7);
    int node = rb * 32 + r;
    int k = s * 32 + (c & 3) * 8;
    f16x8 o = {};
    if (node < M) {
        const float* xr = x + (size_t)node * 128 + k;
#pragma unroll
        for (int j = 0; j < 8; ++j) {
            float v = xr[j];
            _Float16 hi = (_Float16)v;
            o[j] = (c < 4) ? hi : (_Float16)((v - (float)hi) * 2048.f);
        }
    }
    reinterpret_cast<f16x8*>(xp)[g] = o;
}

// Frag-major B packing: flat i = ((s*G + g)*64 + l)*8 + j, G=N/16;
// value = W[k][n], n = g*16 + (l&15), k = s*32 + (l>>4)*8 + j.
struct WSeg { const float* src; _Float16* dh; _Float16* dl; int K; int N; };
struct WSegs { WSeg s[8]; };

__global__ void pack_b_kernel(WSegs segs) {
    WSeg sg = segs.s[blockIdx.y];
    int i = blockIdx.x * 256 + threadIdx.x;
    if (i >= sg.K * sg.N) return;
    int G = sg.N >> 4;
    int s = i / (G * 512);
    int r = i - s * (G * 512);
    int g = r >> 9;
    int r2 = r & 511;
    int l = r2 >> 3, j = r2 & 7;
    int n = g * 16 + (l & 15);
    int k = s * 32 + (l >> 4) * 8 + j;
    float w = sg.src[(size_t)k * sg.N + n];
    _Float16 hi = (_Float16)w;
    sg.dh[i] = hi;
    sg.dl[i] = (_Float16)((w - (float)hi) * 2048.f);
}

// --------------------- global->LDS 16B helper -------------------------------
__device__ __forceinline__ void gload_lds16(const _Float16* src, char* dst_wavebase) {
#if __has_builtin(__builtin_amdgcn_global_load_lds)
    __builtin_amdgcn_global_load_lds(
        (const __attribute__((address_space(1))) void*)src,
        (__attribute__((address_space(3))) void*)dst_wavebase, 16, 0, 0);
#else
    *reinterpret_cast<f16x8*>(dst_wavebase + (threadIdx.x & 63) * 16) =
        *reinterpret_cast<const f16x8*>(src);
#endif
}

// ---------------------------------------------------------------------------
// Split-fp16 MFMA GEMM, all-A-staged. 256 thr = 4 waves, 32 rows/block.
// Stage NS slabs (one contiguous NS*4 KB read) -> one __syncthreads ->
// barrier-free K-loop: per slab 6 B-frag global loads (frag-major, L2-hot),
// 2*MT ds_read_b128 A-frags, 9*2*MT MFMAs.
//   NN=192: MT=2, wave w -> rows 0-31, cols [w*48,+48)
//   NN=96 : MT=1, wave w -> rows [(w>>1)*16,+16), cols [(w&1)*48,+48)
// OM bit0: fp32 row-major out Cf. OM bit1: block-packed split out Cp (NN/32
// slabs). rowscale applied last.
// ---------------------------------------------------------------------------
template <int KK, int NN, int ACT, int OM>
__global__ __launch_bounds__(256, 2) void mfma_gemm(
    const _Float16* __restrict__ Ap,
    const _Float16* __restrict__ Bph, const _Float16* __restrict__ Bpl,
    const float* __restrict__ bias, const float* __restrict__ rowscale,
    float* __restrict__ Cf, _Float16* __restrict__ Cp, int M) {
    constexpr int NS = KK / 32;
    constexpr int G = NN / 16;
    constexpr int MT = (NN == 192) ? 2 : 1;
    constexpr int NSO = NN / 32;  // output slabs for packed writes
    __shared__ __align__(16) char smem[NS * 4096];

    const int tid = threadIdx.x;
    const int wave = tid >> 6, lane = tid & 63;
    const int quad = lane >> 4, l16 = lane & 15;
    const int m0 = (NN == 192) ? 0 : (wave >> 1) * 16;
    const int n0 = (NN == 192) ? wave * 48 : (wave & 1) * 48;
    const int g0 = n0 >> 4;
    const int rb = blockIdx.x;
    const int row0 = rb * 32;
    const int wb = (tid & ~63) * 16;

    // stage the whole A tile (contiguous) and sync once
    const _Float16* abase = Ap + (size_t)rb * NS * 2048;
#pragma unroll
    for (int s = 0; s < NS; ++s)
        gload_lds16(abase + s * 2048 + tid * 8, smem + s * 4096 + wb);

    f32x4 acc[MT][3], acc2[MT][3];
#pragma unroll
    for (int mt = 0; mt < MT; ++mt)
#pragma unroll
        for (int nt = 0; nt < 3; ++nt) {
            acc[mt][nt] = (f32x4){0.f, 0.f, 0.f, 0.f};
            acc2[mt][nt] = (f32x4){0.f, 0.f, 0.f, 0.f};
        }

    __syncthreads();  // the ONLY barrier: drains the 24 KB A burst

#pragma unroll
    for (int s = 0; s < NS; ++s) {
        f16x8 bh[3], bl[3];
#pragma unroll
        for (int nt = 0; nt < 3; ++nt) {
            size_t o = ((size_t)(s * G + g0 + nt) * 64 + lane) * 8;
            bh[nt] = *reinterpret_cast<const f16x8*>(Bph + o);
            bl[nt] = *reinterpret_cast<const f16x8*>(Bpl + o);
        }
        const _Float16* As = (const _Float16*)(smem + s * 4096);
        f16x8 ah[MT], al[MT];
#pragma unroll
        for (int mt = 0; mt < MT; ++mt) {
            int R = m0 + mt * 16 + l16;
            int ph = quad ^ (R & 7);
            ah[mt] = *reinterpret_cast<const f16x8*>(As + R * 64 + ph * 8);
            al[mt] = *reinterpret_cast<const f16x8*>(As + R * 64 + (ph ^ 4) * 8);
        }
#pragma unroll
        for (int mt = 0; mt < MT; ++mt)
#pragma unroll
            for (int nt = 0; nt < 3; ++nt) {
                acc[mt][nt] = __builtin_amdgcn_mfma_f32_16x16x32_f16(ah[mt], bh[nt], acc[mt][nt], 0, 0, 0);
                acc2[mt][nt] = __builtin_amdgcn_mfma_f32_16x16x32_f16(ah[mt], bl[nt], acc2[mt][nt], 0, 0, 0);
                acc2[mt][nt] = __builtin_amdgcn_mfma_f32_16x16x32_f16(al[mt], bh[nt], acc2[mt][nt], 0, 0, 0);
            }
    }

    // epilogue: C/D layout col=lane&15, row=quad*4+reg
    float bv[3];
#pragma unroll
    for (int nt = 0; nt < 3; ++nt) bv[nt] = bias ? bias[n0 + nt * 16 + l16] : 0.f;
#pragma unroll
    for (int mt = 0; mt < MT; ++mt)
#pragma unroll
        for (int i = 0; i < 4; ++i) {
            int row = row0 + m0 + mt * 16 + quad * 4 + i;
            if (row < M) {
                float rs = rowscale ? rowscale[row] : 1.f;
#pragma unroll
                for (int nt = 0; nt < 3; ++nt) {
                    int col = n0 + nt * 16 + l16;
                    float v = acc[mt][nt][i] + acc2[mt][nt][i] * (1.f / 2048.f) + bv[nt];
                    if (ACT == 1) v = fmaxf(v, 0.f);
                    v *= rs;
                    if (OM & 1) Cf[(size_t)row * NN + col] = v;
                    if (OM & 2) {
                        _Float16 hi = (_Float16)v;
                        _Float16 lo = (_Float16)((v - (float)hi) * 2048.f);
                        int r = row & 31;
                        int os = col >> 5, oc = (col >> 3) & 3, j = col & 7;
                        size_t base = ((size_t)((row >> 5) * NSO + os) * 32 + r) * 64;
                        int ph2 = oc ^ (r & 7);
                        Cp[base + ph2 * 8 + j] = hi;
                        Cp[base + (ph2 ^ 4) * 8 + j] = lo;
                    }
                }
            }
        }
}

// ---------------------------------------------------------------------------
// fp32 aggregation (round-3 gather path, untouched: 94 us / 311 MB floor).
// h = h + relu(dinv[n]*(msc[n] + sum_e msc[src_e]) + B); h is block-packed
// split-fp16 (6 slabs), reconstructed/re-split in fp32 here.
// ---------------------------------------------------------------------------
__global__ __launch_bounds__(256) void aggregate_kernel(
    const float* __restrict__ msc, const int* __restrict__ csr,
    const int* __restrict__ rowptr, const float* __restrict__ dinv,
    const float* __restrict__ bias, _Float16* __restrict__ h, int M) {
    int wid = (blockIdx.x * 256 + threadIdx.x) >> 6;
    int lane = threadIdx.x & 63;
    if (wid >= M || lane >= 48) return;
    const float4* base = reinterpret_cast<const float4*>(msc);
    float4 a = base[(size_t)wid * 48 + lane];  // self-loop (already * dinv[wid])
    float4 a2 = make_float4(0.f, 0.f, 0.f, 0.f);
    int beg = rowptr[wid], end = rowptr[wid + 1];
    int e = beg;
    for (; e + 1 < end; e += 2) {
        int s0 = csr[e], s1 = csr[e + 1];
        float4 v0 = base[(size_t)s0 * 48 + lane];
        float4 v1 = base[(size_t)s1 * 48 + lane];
        a.x += v0.x; a.y += v0.y; a.z += v0.z; a.w += v0.w;
        a2.x += v1.x; a2.y += v1.y; a2.z += v1.z; a2.w += v1.w;
    }
    if (e < end) {
        int s = csr[e];
        float4 v = base[(size_t)s * 48 + lane];
        a.x += v.x; a.y += v.y; a.z += v.z; a.w += v.w;
    }
    a.x += a2.x; a.y += a2.y; a.z += a2.z; a.w += a2.w;
    float dn = dinv[wid];
    float4 b = reinterpret_cast<const float4*>(bias)[lane];

    // packed-h address for features f0 = lane*4 .. +4 (one octet half)
    int f0 = lane * 4;
    int s = f0 >> 5, c = (f0 >> 3) & 3, jh = (f0 >> 2) & 1;
    int r = wid & 31;
    size_t pbase = ((size_t)((wid >> 5) * 6 + s) * 32 + r) * 64;
    int ph = c ^ (r & 7);
    f16x4* hp = reinterpret_cast<f16x4*>(h + pbase + ph * 8 + jh * 4);
    f16x4* lp = reinterpret_cast<f16x4*>(h + pbase + (ph ^ 4) * 8 + jh * 4);
    f16x4 hh = *hp, hl = *lp;
    float4 hv;
    hv.x = (float)hh[0] + (float)hl[0] * (1.f / 2048.f) + fmaxf(a.x * dn + b.x, 0.f);
    hv.y = (float)hh[1] + (float)hl[1] * (1.f / 2048.f) + fmaxf(a.y * dn + b.y, 0.f);
    hv.z = (float)hh[2] + (float)hl[2] * (1.f / 2048.f) + fmaxf(a.z * dn + b.z, 0.f);
    hv.w = (float)hh[3] + (float)hl[3] * (1.f / 2048.f) + fmaxf(a.w * dn + b.w, 0.f);
    f16x4 nh = {(_Float16)hv.x, (_Float16)hv.y, (_Float16)hv.z, (_Float16)hv.w};
    f16x4 nl = {(_Float16)((hv.x - (float)nh[0]) * 2048.f),
                (_Float16)((hv.y - (float)nh[1]) * 2048.f),
                (_Float16)((hv.z - (float)nh[2]) * 2048.f),
                (_Float16)((hv.w - (float)nh[3]) * 2048.f)};
    *hp = nh;
    *lp = nl;
}

// ---------------------------------------------------------------------------
// Tail: pos = p2@Wp3+bp3; rad = sigmoid(r@Wr2+br2); out = pos/(|pos|+1e-8)*rad
// ---------------------------------------------------------------------------
__global__ void finalize_kernel(const float* __restrict__ p2, const float* __restrict__ rbuf,
                                const float* __restrict__ Wp3, const float* __restrict__ bp3,
                                const float* __restrict__ Wr2, const float* __restrict__ br2,
                                float* __restrict__ out, int M) {
    int n = blockIdx.x * 256 + threadIdx.x;
    if (n >= M) return;
    const float4* p = reinterpret_cast<const float4*>(p2 + (size_t)n * 96);
    const float4* r = reinterpret_cast<const float4*>(rbuf + (size_t)n * 96);
    float a0 = 0.f, a1 = 0.f, rr = 0.f;
#pragma unroll
    for (int q = 0; q < 24; q++) {
        float4 pv = p[q];
        float4 rv = r[q];
        float4 w01 = reinterpret_cast<const float4*>(Wp3)[2 * q];
        float4 w23 = reinterpret_cast<const float4*>(Wp3)[2 * q + 1];
        a0 += pv.x * w01.x + pv.y * w01.z + pv.z * w23.x + pv.w * w23.z;
        a1 += pv.x * w01.y + pv.y * w01.w + pv.z * w23.y + pv.w * w23.w;
        float4 wr = reinterpret_cast<const float4*>(Wr2)[q];
        rr += rv.x * wr.x + rv.y * wr.y + rv.z * wr.z + rv.w * wr.w;
    }
    a0 += bp3[0];
    a1 += bp3[1];
    rr += br2[0];
    float radius = 1.f / (1.f + expf(-rr));
    float nrm = sqrtf(a0 * a0 + a1 * a1) + 1e-8f;
    float s = radius / nrm;
    out[(size_t)n * 2 + 0] = a0 * s;
    out[(size_t)n * 2 + 1] = a1 * s;
}

extern "C" void kernel_launch(void* const* d_in, const int* in_sizes, int n_in,
                              void* d_out, int out_size, void* d_ws, size_t ws_size,
                              hipStream_t stream) {
    const float* x     = (const float*)d_in[0];
    const int*   ei    = (const int*)d_in[1];
    const float* Wp    = (const float*)d_in[2];
    const float* bp    = (const float*)d_in[3];
    const float* convW = (const float*)d_in[4];
    const float* convB = (const float*)d_in[5];
    const float* Wp1   = (const float*)d_in[6];
    const float* bp1   = (const float*)d_in[7];
    const float* Wp2   = (const float*)d_in[8];
    const float* bp2   = (const float*)d_in[9];
    const float* Wp3   = (const float*)d_in[10];
    const float* bp3   = (const float*)d_in[11];
    const float* Wr1   = (const float*)d_in[12];
    const float* br1   = (const float*)d_in[13];
    const float* Wr2   = (const float*)d_in[14];
    const float* br2   = (const float*)d_in[15];
    float* out = (float*)d_out;

    const int M = in_sizes[0] / 128;  // 50000
    const int E = in_sizes[1] / 2;    // 800000
    const int* srcI = ei;
    const int* dstI = ei + E;
    const int RB = (M + 31) / 32;     // 1563 rowblocks

    char* w = (char*)d_ws;
    size_t off = 0;
    auto alloc = [&](size_t b) { size_t o = off; off += (b + 255) & ~(size_t)255; return o; };
    float*    msc  = (float*)(w + alloc((size_t)RB * 6 * 4096));  // 38.41 MB; reused as p1 packed
    _Float16* hpk  = (_Float16*)(w + alloc((size_t)RB * 6 * 4096));  // h block-packed
    char*     xreg = w + alloc((size_t)RB * 4 * 4096);  // x packed; later p2 fp32 (19.2<=25.6MB)
    float*    rb_  = (float*)(w + alloc((size_t)M * 96 * 4));
    _Float16* WpPh  = (_Float16*)(w + alloc((size_t)128 * 192 * 2));
    _Float16* WpPl  = (_Float16*)(w + alloc((size_t)128 * 192 * 2));
    _Float16* cWPh  = (_Float16*)(w + alloc((size_t)4 * 192 * 192 * 2));
    _Float16* cWPl  = (_Float16*)(w + alloc((size_t)4 * 192 * 192 * 2));
    _Float16* Wp1Ph = (_Float16*)(w + alloc((size_t)192 * 192 * 2));
    _Float16* Wp1Pl = (_Float16*)(w + alloc((size_t)192 * 192 * 2));
    _Float16* Wp2Ph = (_Float16*)(w + alloc((size_t)192 * 96 * 2));
    _Float16* Wp2Pl = (_Float16*)(w + alloc((size_t)192 * 96 * 2));
    _Float16* Wr1Ph = (_Float16*)(w + alloc((size_t)192 * 96 * 2));
    _Float16* Wr1Pl = (_Float16*)(w + alloc((size_t)192 * 96 * 2));
    int*      cnt    = (int*)(w + alloc((size_t)M * 4));
    float*    dinv   = (float*)(w + alloc((size_t)M * 4));
    int*      rowptr = (int*)(w + alloc((size_t)(M + 1) * 4));
    int*      cursor = (int*)(w + alloc((size_t)M * 4));
    int*      csr    = (int*)(w + alloc((size_t)E * 4));
    int*      bsum   = (int*)(w + alloc(256 * 4));
    int*      boff   = (int*)(w + alloc(256 * 4));

    _Float16* xpk = (_Float16*)xreg;        // x packed (4 slabs)
    float*    p2  = (float*)xreg;           // alias: x packed dead after proj
    _Float16* p1pk = (_Float16*)msc;        // alias: msc dead after last aggregate

    hipMemsetAsync(cnt, 0, (size_t)M * 4, stream);
    hipMemsetAsync(cursor, 0, (size_t)M * 4, stream);

    // graph setup
    count_kernel<<<(E + 255) / 256, 256, 0, stream>>>(dstI, E, cnt);
    int nb = (M + 255) / 256;
    scan1_kernel<<<nb, 256, 0, stream>>>(cnt, M, rowptr, bsum, dinv);
    scan2_kernel<<<1, 256, 0, stream>>>(bsum, nb, boff);
    scan3_kernel<<<(M + 256) / 256, 256, 0, stream>>>(rowptr, M, E, boff);
    fill_kernel<<<(E + 255) / 256, 256, 0, stream>>>(srcI, dstI, E, rowptr, cursor, csr);

    // conversions
    int xchunks = RB * 4 * 256;
    convert_x_kernel<<<(xchunks + 255) / 256, 256, 0, stream>>>(x, xpk, M, xchunks);
    WSegs segs;
    segs.s[0] = {Wp, WpPh, WpPl, 128, 192};
    segs.s[1] = {convW + 0 * 192 * 192, cWPh + 0 * 192 * 192, cWPl + 0 * 192 * 192, 192, 192};
    segs.s[2] = {convW + 1 * 192 * 192, cWPh + 1 * 192 * 192, cWPl + 1 * 192 * 192, 192, 192};
    segs.s[3] = {convW + 2 * 192 * 192, cWPh + 2 * 192 * 192, cWPl + 2 * 192 * 192, 192, 192};
    segs.s[4] = {convW + 3 * 192 * 192, cWPh + 3 * 192 * 192, cWPl + 3 * 192 * 192, 192, 192};
    segs.s[5] = {Wp1, Wp1Ph, Wp1Pl, 192, 192};
    segs.s[6] = {Wp2, Wp2Ph, Wp2Pl, 192, 96};
    segs.s[7] = {Wr1, Wr1Ph, Wr1Pl, 192, 96};
    pack_b_kernel<<<dim3(144, 8), 256, 0, stream>>>(segs);

    // h = x @ Wp + bp -> packed planes
    mfma_gemm<128, 192, 0, 2><<<RB, 256, 0, stream>>>(
        xpk, WpPh, WpPl, bp, nullptr, nullptr, hpk, M);
    // 4 GCN layers
    for (int i = 0; i < 4; i++) {
        mfma_gemm<192, 192, 0, 1><<<RB, 256, 0, stream>>>(
            hpk, cWPh + (size_t)i * 192 * 192, cWPl + (size_t)i * 192 * 192,
            nullptr, dinv, msc, nullptr, M);
        aggregate_kernel<<<(M + 3) / 4, 256, 0, stream>>>(
            msc, csr, rowptr, dinv, convB + (size_t)i * 192, hpk, M);
    }
    // heads
    mfma_gemm<192, 192, 1, 2><<<RB, 256, 0, stream>>>(
        hpk, Wp1Ph, Wp1Pl, bp1, nullptr, nullptr, p1pk, M);
    mfma_gemm<192, 96, 1, 1><<<RB, 256, 0, stream>>>(
        p1pk, Wp2Ph, Wp2Pl, bp2, nullptr, p2, nullptr, M);
    mfma_gemm<192, 96, 1, 1><<<RB, 256, 0, stream>>>(
        hpk, Wr1Ph, Wr1Pl, br1, nullptr, rb_, nullptr, M);
    finalize_kernel<<<(M + 255) / 256, 256, 0, stream>>>(p2, rb_, Wp3, bp3, Wr2, br2, out, M);
}